// Round 4
// baseline (916.187 us; speedup 1.0000x reference)
//
#include <hip/hip_runtime.h>

#define NDIM 128
#define EDIM 64
#define BN_EPS 1e-5f
#define CHUNK 96

// ---------------------------------------------------------------------------
// CSR build step 1: degree histogram over dst.
// ---------------------------------------------------------------------------
__global__ __launch_bounds__(256) void hist_k(
    const int* __restrict__ ei, int* __restrict__ deg, int E)
{
    const int e = blockIdx.x * blockDim.x + threadIdx.x;
    if (e < E) atomicAdd(&deg[ei[E + e]], 1);
}

// ---------------------------------------------------------------------------
// CSR build step 2: exclusive scan of deg -> rowptr + cursor.
// ---------------------------------------------------------------------------
__global__ __launch_bounds__(1024) void scan_build(
    int* __restrict__ cursor, int* __restrict__ rowptr, int N)
{
    __shared__ int wsums[16];
    __shared__ int run_s;
    const int tid  = threadIdx.x;
    const int lane = tid & 63;
    const int w    = tid >> 6;
    if (tid == 0) run_s = 0;
    __syncthreads();
    for (int base = 0; base < N; base += 1024) {
        const int i = base + tid;
        const int v = (i < N) ? cursor[i] : 0;
        int incl = v;
#pragma unroll
        for (int off = 1; off < 64; off <<= 1) {
            int t = __shfl_up(incl, off, 64);
            if (lane >= off) incl += t;
        }
        if (lane == 63) wsums[w] = incl;
        __syncthreads();
        if (w == 0) {
            int s = (lane < 16) ? wsums[lane] : 0;
#pragma unroll
            for (int off = 1; off < 16; off <<= 1) {
                int t = __shfl_up(s, off, 64);
                if (lane >= off) s += t;
            }
            if (lane < 16) wsums[lane] = s;
        }
        __syncthreads();
        const int waveoff = (w > 0) ? wsums[w - 1] : 0;
        const int run = run_s;
        const int excl = run + waveoff + incl - v;
        if (i < N) { rowptr[i] = excl; cursor[i] = excl; }
        __syncthreads();
        if (tid == 0) run_s += wsums[15];
        __syncthreads();
    }
    if (tid == 0) rowptr[N] = run_s;
}

// ---------------------------------------------------------------------------
// CSR build step 3: scatter (src, edge_id) pairs + dst into slot order.
// ea stays in edge order; the gather reads it through se.y.
// ---------------------------------------------------------------------------
__global__ __launch_bounds__(256) void scatter_k(
    const int* __restrict__ ei, int* __restrict__ cursor,
    int2* __restrict__ sep, int* __restrict__ dstp, int E)
{
    const int e = blockIdx.x * blockDim.x + threadIdx.x;
    if (e < E) {
        const int d = ei[E + e];
        const int p = atomicAdd(&cursor[d], 1);
        sep[p]  = make_int2(ei[e], e);
        dstp[p] = d;
    }
}

// ---------------------------------------------------------------------------
// Edge pass: slot-parallel segmented gather. Block = 128 threads (feature-
// parallel) over CHUNK consecutive slots (sorted by dst). ea row (via eid)
// staged in double-buffered LDS; x row + scalars software-pipelined; per-
// feature register accumulator flushed by atomicAdd on dst change.
// ---------------------------------------------------------------------------
__global__ __launch_bounds__(128) void edge_gather(
    const float* __restrict__ xnode,  // [N,128]
    const float* __restrict__ ea,     // [E,64] edge order
    const int2*  __restrict__ sep,    // [E] slot-ordered (src, eid)
    const int*   __restrict__ dstp,   // [E] slot-ordered dst (non-decreasing)
    const float* __restrict__ We,     // [64,128]
    const float* __restrict__ be,     // [128]
    float*       __restrict__ aggr,   // [N,128] pre-zeroed
    int E)
{
    __shared__ __align__(16) float buf[2][EDIM];

    const int j = threadIdx.x;
    float w[EDIM];
#pragma unroll
    for (int k = 0; k < EDIM; ++k) w[k] = We[k * NDIM + j];
    const float bj = be[j];

    const int c0 = blockIdx.x * CHUNK;
    if (c0 >= E) return;
    const int cend = min(c0 + CHUNK, E);

    // ---- preamble: slot c0 in flight, slot c0+1 scalars loaded ----
    int2 se_cur = sep[c0];
    int  d_cur  = dstp[c0];
    float xv    = xnode[(size_t)se_cur.x * NDIM + j];
    int2 se_nxt = make_int2(0, 0);
    int  d_nxt  = 0;
    if (c0 + 1 < cend) { se_nxt = sep[c0 + 1]; d_nxt = dstp[c0 + 1]; }
    if (j < EDIM) buf[0][j] = ea[(size_t)se_cur.y * EDIM + j];

    float acc = 0.f;
    int bufi = 0;

    for (int p = c0; p < cend; ++p) {
        __syncthreads();   // buf[bufi] ready; prior reads of buf[bufi^1] done
        const bool hn  = (p + 1 < cend);
        const bool hnn = (p + 2 < cend);

        // issue prefetches for p+1 (x row, ea row) and p+2 (scalars)
        int2 se_nn = make_int2(0, 0);
        int  d_nn  = 0;
        if (hnn) { se_nn = sep[p + 2]; d_nn = dstp[p + 2]; }
        float x_nxt = 0.f, ea_nxt = 0.f;
        if (hn) {
            x_nxt = xnode[(size_t)se_nxt.x * NDIM + j];
            if (j < EDIM) ea_nxt = ea[(size_t)se_nxt.y * EDIM + j];
        }

        // compute current slot from buf[bufi]
        float a0 = 0.f, a1 = 0.f, a2 = 0.f, a3 = 0.f;
#pragma unroll
        for (int k4 = 0; k4 < EDIM / 4; ++k4) {
            const float4 v = *reinterpret_cast<const float4*>(&buf[bufi][4 * k4]);
            a0 += v.x * w[4 * k4 + 0];
            a1 += v.y * w[4 * k4 + 1];
            a2 += v.z * w[4 * k4 + 2];
            a3 += v.w * w[4 * k4 + 3];
        }
        acc += fmaxf(xv + (bj + (a0 + a1) + (a2 + a3)), 0.f);

        // stage next ea row into the other buffer
        if (hn && j < EDIM) buf[bufi ^ 1][j] = ea_nxt;

        // flush on dst change / chunk end
        if (!hn || d_nxt != d_cur) {
            atomicAdd(&aggr[(size_t)d_cur * NDIM + j], acc);
            acc = 0.f;
        }

        // rotate pipeline
        xv = x_nxt;
        if (hn) d_cur = d_nxt;
        se_cur = se_nxt;
        se_nxt = se_nn; d_nxt = d_nn;
        bufi ^= 1;
    }
}

// ---------------------------------------------------------------------------
// Node MLP: out = [relu]( relu((xin+aggr) @ Wa + ba) @ Wb + bb )
// ---------------------------------------------------------------------------
template <bool FINAL_RELU, bool STATS>
__global__ __launch_bounds__(256) void node_mlp(
    const float* xin,                   // may alias out
    const float* __restrict__ aggr,
    const float* __restrict__ Wa, const float* __restrict__ ba,
    const float* __restrict__ Wb, const float* __restrict__ bb,
    float* out,
    float* __restrict__ stats,
    int N)
{
    __shared__ __align__(16) float in_s[NDIM];
    __shared__ __align__(16) float t_s[NDIM];
    __shared__ __align__(16) float partial[NDIM];

    const int tid  = threadIdx.x;
    const int lane = tid & 63;
    const int w    = tid >> 6;
    const int kh   = w >> 1;
    const int jh   = w & 1;
    const int jf   = jh * 64 + lane;

    float wa[64], wb[64];
#pragma unroll
    for (int kk = 0; kk < 64; ++kk) {
        wa[kk] = Wa[(size_t)(kh * 64 + kk) * NDIM + jf];
        wb[kk] = Wb[(size_t)(kh * 64 + kk) * NDIM + jf];
    }
    const float baj = ba[jf];
    const float bbj = bb[jf];

    float ssum = 0.f, ssq = 0.f;

    for (int i = blockIdx.x; i < N; i += gridDim.x) {
        if (tid < NDIM)
            in_s[tid] = xin[(size_t)i * NDIM + tid] + aggr[(size_t)i * NDIM + tid];
        __syncthreads();

        float a0 = 0.f, a1 = 0.f, a2 = 0.f, a3 = 0.f;
#pragma unroll
        for (int k4 = 0; k4 < 16; ++k4) {
            const float4 v = *reinterpret_cast<const float4*>(&in_s[kh * 64 + 4 * k4]);
            a0 += v.x * wa[4 * k4 + 0];
            a1 += v.y * wa[4 * k4 + 1];
            a2 += v.z * wa[4 * k4 + 2];
            a3 += v.w * wa[4 * k4 + 3];
        }
        const float acc = (a0 + a1) + (a2 + a3);
        if (kh == 1) partial[jf] = acc;
        __syncthreads();
        if (kh == 0) {
            float t = acc + partial[jf] + baj;
            t_s[jf] = fmaxf(t, 0.f);
        }
        __syncthreads();

        float c0 = 0.f, c1 = 0.f, c2 = 0.f, c3 = 0.f;
#pragma unroll
        for (int k4 = 0; k4 < 16; ++k4) {
            const float4 v = *reinterpret_cast<const float4*>(&t_s[kh * 64 + 4 * k4]);
            c0 += v.x * wb[4 * k4 + 0];
            c1 += v.y * wb[4 * k4 + 1];
            c2 += v.z * wb[4 * k4 + 2];
            c3 += v.w * wb[4 * k4 + 3];
        }
        const float acc2 = (c0 + c1) + (c2 + c3);
        if (kh == 1) partial[jf] = acc2;
        __syncthreads();
        if (kh == 0) {
            float o = acc2 + partial[jf] + bbj;
            if (FINAL_RELU) o = fmaxf(o, 0.f);
            out[(size_t)i * NDIM + jf] = o;
            if (STATS) { ssum += o; ssq += o * o; }
        }
        __syncthreads();
    }

    if (STATS && kh == 0) {
        atomicAdd(&stats[jf], ssum);
        atomicAdd(&stats[NDIM + jf], ssq);
    }
}

// ---------------------------------------------------------------------------
// BatchNorm apply (in place).
// ---------------------------------------------------------------------------
__global__ __launch_bounds__(256) void bn_apply(
    float* out,
    const float* __restrict__ stats,
    const float* __restrict__ gamma,
    const float* __restrict__ beta,
    int N)
{
    __shared__ float sc_s[NDIM];
    __shared__ float sh_s[NDIM];
    const float invN = 1.f / (float)N;
    if (threadIdx.x < NDIM) {
        const int f = threadIdx.x;
        const float mean = stats[f] * invN;
        const float var  = stats[NDIM + f] * invN - mean * mean;
        const float sc   = gamma[f] * rsqrtf(var + BN_EPS);
        sc_s[f] = sc;
        sh_s[f] = beta[f] - mean * sc;
    }
    __syncthreads();

    const int total4 = N * (NDIM / 4);
    float4* o4 = reinterpret_cast<float4*>(out);
    for (int idx = blockIdx.x * blockDim.x + threadIdx.x; idx < total4;
         idx += gridDim.x * blockDim.x) {
        const int fb = (idx & 31) * 4;
        float4 p = o4[idx];
        p.x = p.x * sc_s[fb + 0] + sh_s[fb + 0];
        p.y = p.y * sc_s[fb + 1] + sh_s[fb + 1];
        p.z = p.z * sc_s[fb + 2] + sh_s[fb + 2];
        p.w = p.w * sc_s[fb + 3] + sh_s[fb + 3];
        o4[idx] = p;
    }
}

// ---------------------------------------------------------------------------
extern "C" void kernel_launch(void* const* d_in, const int* in_sizes, int n_in,
                              void* d_out, int out_size, void* d_ws, size_t ws_size,
                              hipStream_t stream)
{
    const float* x    = (const float*)d_in[0];
    const int*   ei   = (const int*)  d_in[1];
    const float* ea   = (const float*)d_in[2];
    const float* We1  = (const float*)d_in[3];
    const float* be1  = (const float*)d_in[4];
    const float* W1   = (const float*)d_in[5];
    const float* b1   = (const float*)d_in[6];
    const float* W2   = (const float*)d_in[7];
    const float* b2   = (const float*)d_in[8];
    const float* We2  = (const float*)d_in[9];
    const float* be2  = (const float*)d_in[10];
    const float* W3   = (const float*)d_in[11];
    const float* b3   = (const float*)d_in[12];
    const float* W4   = (const float*)d_in[13];
    const float* b4   = (const float*)d_in[14];
    const float* gamma = (const float*)d_in[15];
    const float* beta  = (const float*)d_in[16];

    const int N = in_sizes[0] / NDIM;
    const int E = in_sizes[1] / 2;

    // workspace layout
    float* aggr   = (float*)d_ws;                        // [N*128]
    int*   rowptr = (int*)(aggr + (size_t)N * NDIM);     // [N+1]
    int*   cursor = rowptr + (N + 1);                    // [N]
    int*   dstp   = cursor + N;                          // [E]
    int2*  sep    = (int2*)(dstp + E);                   // [E] (8B aligned: offsets even)
    float* stats  = (float*)(sep + E);                   // [256]
    float* h      = (float*)d_out;

    hipMemsetAsync(cursor, 0, (size_t)N * sizeof(int), stream);
    hipMemsetAsync(stats, 0, 2 * NDIM * sizeof(float), stream);

    // ---- CSR build (shared by both conv layers) ----
    hist_k<<<(E + 255) / 256, 256, 0, stream>>>(ei, cursor, E);
    scan_build<<<1, 1024, 0, stream>>>(cursor, rowptr, N);
    scatter_k<<<(E + 255) / 256, 256, 0, stream>>>(ei, cursor, sep, dstp, E);

    const int egrid = (E + CHUNK - 1) / CHUNK;

    // ---- conv1 ----
    hipMemsetAsync(aggr, 0, (size_t)N * NDIM * sizeof(float), stream);
    edge_gather<<<egrid, 128, 0, stream>>>(x, ea, sep, dstp, We1, be1, aggr, E);
    node_mlp<true, false><<<2048, 256, 0, stream>>>(x, aggr, W1, b1, W2, b2,
                                                    h, nullptr, N);
    // ---- conv2 ----
    hipMemsetAsync(aggr, 0, (size_t)N * NDIM * sizeof(float), stream);
    edge_gather<<<egrid, 128, 0, stream>>>(h, ea, sep, dstp, We2, be2, aggr, E);
    node_mlp<false, true><<<2048, 256, 0, stream>>>(h, aggr, W3, b3, W4, b4,
                                                    h, stats, N);
    // ---- batch norm ----
    bn_apply<<<1024, 256, 0, stream>>>(h, stats, gamma, beta, N);
}

// Round 5
// 658.438 us; speedup vs baseline: 1.3915x; 1.3915x over previous
//
#include <hip/hip_runtime.h>

#define NDIM 128
#define EDIM 64
#define BN_EPS 1e-5f
#define SPAN 64          // slots per wave
#define WPB  4           // waves per block
#define LPAD (NDIM + 4)  // LDS row pitch (bank-friendly)

typedef __attribute__((ext_vector_type(8))) short short8v;
typedef __attribute__((ext_vector_type(4))) float float4v;

static __device__ __forceinline__ unsigned short f2bf(float f) {
    union { float f; unsigned u; } c; c.f = f;
    const unsigned r = (c.u + 0x7fffu + ((c.u >> 16) & 1u)) >> 16;
    return (unsigned short)r;
}

// ---------------------------------------------------------------------------
// CSR build step 1: degree histogram over dst.
// ---------------------------------------------------------------------------
__global__ __launch_bounds__(256) void hist_k(
    const int* __restrict__ ei, int* __restrict__ deg, int E)
{
    const int e = blockIdx.x * blockDim.x + threadIdx.x;
    if (e < E) atomicAdd(&deg[ei[E + e]], 1);
}

// ---------------------------------------------------------------------------
// CSR build step 2: exclusive scan of deg -> rowptr + cursor.
// ---------------------------------------------------------------------------
__global__ __launch_bounds__(1024) void scan_build(
    int* __restrict__ cursor, int* __restrict__ rowptr, int N)
{
    __shared__ int wsums[16];
    __shared__ int run_s;
    const int tid  = threadIdx.x;
    const int lane = tid & 63;
    const int w    = tid >> 6;
    if (tid == 0) run_s = 0;
    __syncthreads();
    for (int base = 0; base < N; base += 1024) {
        const int i = base + tid;
        const int v = (i < N) ? cursor[i] : 0;
        int incl = v;
#pragma unroll
        for (int off = 1; off < 64; off <<= 1) {
            int t = __shfl_up(incl, off, 64);
            if (lane >= off) incl += t;
        }
        if (lane == 63) wsums[w] = incl;
        __syncthreads();
        if (w == 0) {
            int s = (lane < 16) ? wsums[lane] : 0;
#pragma unroll
            for (int off = 1; off < 16; off <<= 1) {
                int t = __shfl_up(s, off, 64);
                if (lane >= off) s += t;
            }
            if (lane < 16) wsums[lane] = s;
        }
        __syncthreads();
        const int waveoff = (w > 0) ? wsums[w - 1] : 0;
        const int run = run_s;
        const int excl = run + waveoff + incl - v;
        if (i < N) { rowptr[i] = excl; cursor[i] = excl; }
        __syncthreads();
        if (tid == 0) run_s += wsums[15];
        __syncthreads();
    }
    if (tid == 0) rowptr[N] = run_s;
}

// ---------------------------------------------------------------------------
// CSR build step 3: scatter src / edge-id / dst into slot order.
// ---------------------------------------------------------------------------
__global__ __launch_bounds__(256) void scatter_k(
    const int* __restrict__ ei, int* __restrict__ cursor,
    int* __restrict__ srcp, int* __restrict__ eidp, int* __restrict__ dstp, int E)
{
    const int e = blockIdx.x * blockDim.x + threadIdx.x;
    if (e < E) {
        const int d = ei[E + e];
        const int p = atomicAdd(&cursor[d], 1);
        srcp[p] = ei[e];
        eidp[p] = e;
        dstp[p] = d;
    }
}

// ---------------------------------------------------------------------------
// Prep: We [64][128] f32  ->  WeT [128][64] bf16 (K-major per column).
// ---------------------------------------------------------------------------
__global__ __launch_bounds__(64) void prep_we(
    const float* __restrict__ We, unsigned short* __restrict__ WeT)
{
    const int c = blockIdx.x;    // 0..127
    const int k = threadIdx.x;   // 0..63
    WeT[c * EDIM + k] = f2bf(We[k * NDIM + c]);
}

// ---------------------------------------------------------------------------
// Edge pass, MFMA form. Each wave owns SPAN consecutive dst-sorted slots.
// Per 16-slot tile: A(ea rows, f32->bf16) x B(We, register-resident)
// via 16x mfma_f32_16x16x32_bf16 -> P[16][128]; fragments staged to a
// per-wave LDS tile; feature-parallel segmented relu(x[src]+P+be)
// accumulation, atomic flush on dst change. No __syncthreads at all.
// ---------------------------------------------------------------------------
__global__ __launch_bounds__(256) void edge_mfma(
    const float* __restrict__ xnode,          // [N,128]
    const float* __restrict__ ea,             // [E,64] edge order
    const int*   __restrict__ srcp,           // [E] slot-ordered src
    const int*   __restrict__ eidp,           // [E] slot-ordered edge id
    const int*   __restrict__ dstp,           // [E] slot-ordered dst (sorted)
    const unsigned short* __restrict__ WeT,   // [128][64] bf16
    const float* __restrict__ be,             // [128]
    float*       __restrict__ aggr,           // [N,128] pre-zeroed
    int E)
{
    __shared__ float msg[WPB][16][LPAD];

    const int tid   = threadIdx.x;
    const int lane  = tid & 63;
    const int wv    = tid >> 6;
    const int span0 = (blockIdx.x * WPB + wv) * SPAN;
    if (span0 >= E) return;
    const int spanEnd = (span0 + SPAN < E) ? span0 + SPAN : E;

    const int m16 = lane & 15;   // A row (slot-within-tile) / C col-within-ntile
    const int kg  = lane >> 4;   // k-group 0..3

    // B fragments: full We resident (2 k-tiles x 8 n-tiles = 64 VGPR)
    short8v bfrag[2][8];
#pragma unroll
    for (int kk = 0; kk < 2; ++kk)
#pragma unroll
        for (int nt = 0; nt < 8; ++nt) {
            const int col = nt * 16 + m16;
            const int k0  = kk * 32 + kg * 8;
            bfrag[kk][nt] = *reinterpret_cast<const short8v*>(&WeT[col * EDIM + k0]);
        }

    const int c0 = lane, c1 = lane + 64;
    const float be0 = be[c0], be1 = be[c1];

    float a0 = 0.f, a1 = 0.f;
    int dcur = dstp[span0];

    for (int t = 0; t < SPAN / 16; ++t) {
        const int base = span0 + t * 16;
        if (base >= spanEnd) break;

        // ---- A fragments: ea row (f32) -> bf16, 8 k-elems per lane per k-tile
        const int  slot = (base + m16 < E) ? base + m16 : E - 1;
        const long eid  = (long)eidp[slot];
        const float* arow = ea + eid * EDIM;
        short8v afrag[2];
#pragma unroll
        for (int kk = 0; kk < 2; ++kk) {
            const int k0 = kk * 32 + kg * 8;
            const float4 f0 = *reinterpret_cast<const float4*>(arow + k0);
            const float4 f1 = *reinterpret_cast<const float4*>(arow + k0 + 4);
            short8v a;
            a[0] = (short)f2bf(f0.x); a[1] = (short)f2bf(f0.y);
            a[2] = (short)f2bf(f0.z); a[3] = (short)f2bf(f0.w);
            a[4] = (short)f2bf(f1.x); a[5] = (short)f2bf(f1.y);
            a[6] = (short)f2bf(f1.z); a[7] = (short)f2bf(f1.w);
            afrag[kk] = a;
        }

        // ---- P = A x We : 16 MFMAs ----
        float4v acc[8];
#pragma unroll
        for (int nt = 0; nt < 8; ++nt) {
            acc[nt] = (float4v){0.f, 0.f, 0.f, 0.f};
            acc[nt] = __builtin_amdgcn_mfma_f32_16x16x32_bf16(afrag[0], bfrag[0][nt], acc[nt], 0, 0, 0);
            acc[nt] = __builtin_amdgcn_mfma_f32_16x16x32_bf16(afrag[1], bfrag[1][nt], acc[nt], 0, 0, 0);
        }

        // ---- stage to per-wave LDS: D lane layout col=nt*16+m16, row=kg*4+r
#pragma unroll
        for (int nt = 0; nt < 8; ++nt)
#pragma unroll
            for (int r = 0; r < 4; ++r)
                msg[wv][kg * 4 + r][nt * 16 + m16] = acc[nt][r];

        // ---- segmented accumulate over the tile's slots ----
        if (base + 16 <= spanEnd) {
#pragma unroll
            for (int s = 0; s < 16; ++s) {
                const int gs = base + s;
                const int d  = dstp[gs];
                const int sr = srcp[gs];
                if (d != dcur) {
                    atomicAdd(&aggr[(long)dcur * NDIM + c0], a0);
                    atomicAdd(&aggr[(long)dcur * NDIM + c1], a1);
                    a0 = 0.f; a1 = 0.f; dcur = d;
                }
                const float xv0 = xnode[(long)sr * NDIM + c0];
                const float xv1 = xnode[(long)sr * NDIM + c1];
                a0 += fmaxf(xv0 + msg[wv][s][c0] + be0, 0.f);
                a1 += fmaxf(xv1 + msg[wv][s][c1] + be1, 0.f);
            }
        } else {
            for (int s = 0; s < 16; ++s) {
                const int gs = base + s;
                if (gs >= spanEnd) break;
                const int d  = dstp[gs];
                const int sr = srcp[gs];
                if (d != dcur) {
                    atomicAdd(&aggr[(long)dcur * NDIM + c0], a0);
                    atomicAdd(&aggr[(long)dcur * NDIM + c1], a1);
                    a0 = 0.f; a1 = 0.f; dcur = d;
                }
                const float xv0 = xnode[(long)sr * NDIM + c0];
                const float xv1 = xnode[(long)sr * NDIM + c1];
                a0 += fmaxf(xv0 + msg[wv][s][c0] + be0, 0.f);
                a1 += fmaxf(xv1 + msg[wv][s][c1] + be1, 0.f);
            }
        }
    }
    atomicAdd(&aggr[(long)dcur * NDIM + c0], a0);
    atomicAdd(&aggr[(long)dcur * NDIM + c1], a1);
}

// ---------------------------------------------------------------------------
// Node MLP: out = [relu]( relu((xin+aggr) @ Wa + ba) @ Wb + bb )
// ---------------------------------------------------------------------------
template <bool FINAL_RELU, bool STATS>
__global__ __launch_bounds__(256) void node_mlp(
    const float* xin,                   // may alias out
    const float* __restrict__ aggr,
    const float* __restrict__ Wa, const float* __restrict__ ba,
    const float* __restrict__ Wb, const float* __restrict__ bb,
    float* out,
    float* __restrict__ stats,
    int N)
{
    __shared__ __align__(16) float in_s[NDIM];
    __shared__ __align__(16) float t_s[NDIM];
    __shared__ __align__(16) float partial[NDIM];

    const int tid  = threadIdx.x;
    const int lane = tid & 63;
    const int w    = tid >> 6;
    const int kh   = w >> 1;
    const int jh   = w & 1;
    const int jf   = jh * 64 + lane;

    float wa[64], wb[64];
#pragma unroll
    for (int kk = 0; kk < 64; ++kk) {
        wa[kk] = Wa[(size_t)(kh * 64 + kk) * NDIM + jf];
        wb[kk] = Wb[(size_t)(kh * 64 + kk) * NDIM + jf];
    }
    const float baj = ba[jf];
    const float bbj = bb[jf];

    float ssum = 0.f, ssq = 0.f;

    for (int i = blockIdx.x; i < N; i += gridDim.x) {
        if (tid < NDIM)
            in_s[tid] = xin[(size_t)i * NDIM + tid] + aggr[(size_t)i * NDIM + tid];
        __syncthreads();

        float a0 = 0.f, a1 = 0.f, a2 = 0.f, a3 = 0.f;
#pragma unroll
        for (int k4 = 0; k4 < 16; ++k4) {
            const float4 v = *reinterpret_cast<const float4*>(&in_s[kh * 64 + 4 * k4]);
            a0 += v.x * wa[4 * k4 + 0];
            a1 += v.y * wa[4 * k4 + 1];
            a2 += v.z * wa[4 * k4 + 2];
            a3 += v.w * wa[4 * k4 + 3];
        }
        const float acc = (a0 + a1) + (a2 + a3);
        if (kh == 1) partial[jf] = acc;
        __syncthreads();
        if (kh == 0) {
            float t = acc + partial[jf] + baj;
            t_s[jf] = fmaxf(t, 0.f);
        }
        __syncthreads();

        float c0 = 0.f, c1 = 0.f, c2 = 0.f, c3 = 0.f;
#pragma unroll
        for (int k4 = 0; k4 < 16; ++k4) {
            const float4 v = *reinterpret_cast<const float4*>(&t_s[kh * 64 + 4 * k4]);
            c0 += v.x * wb[4 * k4 + 0];
            c1 += v.y * wb[4 * k4 + 1];
            c2 += v.z * wb[4 * k4 + 2];
            c3 += v.w * wb[4 * k4 + 3];
        }
        const float acc2 = (c0 + c1) + (c2 + c3);
        if (kh == 1) partial[jf] = acc2;
        __syncthreads();
        if (kh == 0) {
            float o = acc2 + partial[jf] + bbj;
            if (FINAL_RELU) o = fmaxf(o, 0.f);
            out[(size_t)i * NDIM + jf] = o;
            if (STATS) { ssum += o; ssq += o * o; }
        }
        __syncthreads();
    }

    if (STATS && kh == 0) {
        atomicAdd(&stats[jf], ssum);
        atomicAdd(&stats[NDIM + jf], ssq);
    }
}

// ---------------------------------------------------------------------------
// BatchNorm apply (in place).
// ---------------------------------------------------------------------------
__global__ __launch_bounds__(256) void bn_apply(
    float* out,
    const float* __restrict__ stats,
    const float* __restrict__ gamma,
    const float* __restrict__ beta,
    int N)
{
    __shared__ float sc_s[NDIM];
    __shared__ float sh_s[NDIM];
    const float invN = 1.f / (float)N;
    if (threadIdx.x < NDIM) {
        const int f = threadIdx.x;
        const float mean = stats[f] * invN;
        const float var  = stats[NDIM + f] * invN - mean * mean;
        const float sc   = gamma[f] * rsqrtf(var + BN_EPS);
        sc_s[f] = sc;
        sh_s[f] = beta[f] - mean * sc;
    }
    __syncthreads();

    const int total4 = N * (NDIM / 4);
    float4* o4 = reinterpret_cast<float4*>(out);
    for (int idx = blockIdx.x * blockDim.x + threadIdx.x; idx < total4;
         idx += gridDim.x * blockDim.x) {
        const int fb = (idx & 31) * 4;
        float4 p = o4[idx];
        p.x = p.x * sc_s[fb + 0] + sh_s[fb + 0];
        p.y = p.y * sc_s[fb + 1] + sh_s[fb + 1];
        p.z = p.z * sc_s[fb + 2] + sh_s[fb + 2];
        p.w = p.w * sc_s[fb + 3] + sh_s[fb + 3];
        o4[idx] = p;
    }
}

// ---------------------------------------------------------------------------
extern "C" void kernel_launch(void* const* d_in, const int* in_sizes, int n_in,
                              void* d_out, int out_size, void* d_ws, size_t ws_size,
                              hipStream_t stream)
{
    const float* x    = (const float*)d_in[0];
    const int*   ei   = (const int*)  d_in[1];
    const float* ea   = (const float*)d_in[2];
    const float* We1  = (const float*)d_in[3];
    const float* be1  = (const float*)d_in[4];
    const float* W1   = (const float*)d_in[5];
    const float* b1   = (const float*)d_in[6];
    const float* W2   = (const float*)d_in[7];
    const float* b2   = (const float*)d_in[8];
    const float* We2  = (const float*)d_in[9];
    const float* be2  = (const float*)d_in[10];
    const float* W3   = (const float*)d_in[11];
    const float* b3   = (const float*)d_in[12];
    const float* W4   = (const float*)d_in[13];
    const float* b4   = (const float*)d_in[14];
    const float* gamma = (const float*)d_in[15];
    const float* beta  = (const float*)d_in[16];

    const int N = in_sizes[0] / NDIM;
    const int E = in_sizes[1] / 2;

    // workspace layout (aggr first keeps 16B alignment for WeT)
    float*          aggr   = (float*)d_ws;                       // [N*128]
    unsigned short* WeT1   = (unsigned short*)(aggr + (size_t)N * NDIM); // [128*64]
    unsigned short* WeT2   = WeT1 + NDIM * EDIM;                 // [128*64]
    int*            rowptr = (int*)(WeT2 + NDIM * EDIM);         // [N+1]
    int*            cursor = rowptr + (N + 1);                   // [N]
    int*            srcp   = cursor + N;                         // [E]
    int*            eidp   = srcp + E;                           // [E]
    int*            dstp   = eidp + E;                           // [E]
    float*          stats  = (float*)(dstp + E);                 // [256]
    float*          h      = (float*)d_out;

    hipMemsetAsync(cursor, 0, (size_t)N * sizeof(int), stream);
    hipMemsetAsync(stats, 0, 2 * NDIM * sizeof(float), stream);

    // ---- CSR build (shared by both conv layers) + weight prep ----
    hist_k<<<(E + 255) / 256, 256, 0, stream>>>(ei, cursor, E);
    scan_build<<<1, 1024, 0, stream>>>(cursor, rowptr, N);
    scatter_k<<<(E + 255) / 256, 256, 0, stream>>>(ei, cursor, srcp, eidp, dstp, E);
    prep_we<<<NDIM, EDIM, 0, stream>>>(We1, WeT1);
    prep_we<<<NDIM, EDIM, 0, stream>>>(We2, WeT2);

    const int egrid = (E + WPB * SPAN - 1) / (WPB * SPAN);

    // ---- conv1 ----
    hipMemsetAsync(aggr, 0, (size_t)N * NDIM * sizeof(float), stream);
    edge_mfma<<<egrid, 256, 0, stream>>>(x, ea, srcp, eidp, dstp, WeT1, be1, aggr, E);
    node_mlp<true, false><<<2048, 256, 0, stream>>>(x, aggr, W1, b1, W2, b2,
                                                    h, nullptr, N);
    // ---- conv2 ----
    hipMemsetAsync(aggr, 0, (size_t)N * NDIM * sizeof(float), stream);
    edge_mfma<<<egrid, 256, 0, stream>>>(h, ea, srcp, eidp, dstp, WeT2, be2, aggr, E);
    node_mlp<false, true><<<2048, 256, 0, stream>>>(h, aggr, W3, b3, W4, b4,
                                                    h, stats, N);
    // ---- batch norm ----
    bn_apply<<<1024, 256, 0, stream>>>(h, stats, gamma, beta, N);
}

// Round 6
// 548.034 us; speedup vs baseline: 1.6718x; 1.2015x over previous
//
#include <hip/hip_runtime.h>

#define NDIM 128
#define EDIM 64
#define BN_EPS 1e-5f
#define SPAN 64          // slots per wave
#define WPB  4           // waves per block
#define LPAD (NDIM + 4)  // LDS row pitch (bank-friendly)

typedef __attribute__((ext_vector_type(8))) short short8v;
typedef __attribute__((ext_vector_type(4))) float float4v;

static __device__ __forceinline__ unsigned short f2bf(float f) {
    union { float f; unsigned u; } c; c.f = f;
    const unsigned r = (c.u + 0x7fffu + ((c.u >> 16) & 1u)) >> 16;
    return (unsigned short)r;
}

static __device__ __forceinline__ short8v cvt_row(const float* __restrict__ arow, int k0) {
    const float4 f0 = *reinterpret_cast<const float4*>(arow + k0);
    const float4 f1 = *reinterpret_cast<const float4*>(arow + k0 + 4);
    short8v a;
    a[0] = (short)f2bf(f0.x); a[1] = (short)f2bf(f0.y);
    a[2] = (short)f2bf(f0.z); a[3] = (short)f2bf(f0.w);
    a[4] = (short)f2bf(f1.x); a[5] = (short)f2bf(f1.y);
    a[6] = (short)f2bf(f1.z); a[7] = (short)f2bf(f1.w);
    return a;
}

// ---------------------------------------------------------------------------
// CSR build step 1: degree histogram over dst.
// ---------------------------------------------------------------------------
__global__ __launch_bounds__(256) void hist_k(
    const int* __restrict__ ei, int* __restrict__ deg, int E)
{
    const int e = blockIdx.x * blockDim.x + threadIdx.x;
    if (e < E) atomicAdd(&deg[ei[E + e]], 1);
}

// ---------------------------------------------------------------------------
// CSR build step 2: exclusive scan of deg -> rowptr + cursor.
// ---------------------------------------------------------------------------
__global__ __launch_bounds__(1024) void scan_build(
    int* __restrict__ cursor, int* __restrict__ rowptr, int N)
{
    __shared__ int wsums[16];
    __shared__ int run_s;
    const int tid  = threadIdx.x;
    const int lane = tid & 63;
    const int w    = tid >> 6;
    if (tid == 0) run_s = 0;
    __syncthreads();
    for (int base = 0; base < N; base += 1024) {
        const int i = base + tid;
        const int v = (i < N) ? cursor[i] : 0;
        int incl = v;
#pragma unroll
        for (int off = 1; off < 64; off <<= 1) {
            int t = __shfl_up(incl, off, 64);
            if (lane >= off) incl += t;
        }
        if (lane == 63) wsums[w] = incl;
        __syncthreads();
        if (w == 0) {
            int s = (lane < 16) ? wsums[lane] : 0;
#pragma unroll
            for (int off = 1; off < 16; off <<= 1) {
                int t = __shfl_up(s, off, 64);
                if (lane >= off) s += t;
            }
            if (lane < 16) wsums[lane] = s;
        }
        __syncthreads();
        const int waveoff = (w > 0) ? wsums[w - 1] : 0;
        const int run = run_s;
        const int excl = run + waveoff + incl - v;
        if (i < N) { rowptr[i] = excl; cursor[i] = excl; }
        __syncthreads();
        if (tid == 0) run_s += wsums[15];
        __syncthreads();
    }
    if (tid == 0) rowptr[N] = run_s;
}

// ---------------------------------------------------------------------------
// CSR build step 3: scatter src / edge-id / dst into slot order.
// ---------------------------------------------------------------------------
__global__ __launch_bounds__(256) void scatter_k(
    const int* __restrict__ ei, int* __restrict__ cursor,
    int* __restrict__ srcp, int* __restrict__ eidp, int* __restrict__ dstp, int E)
{
    const int e = blockIdx.x * blockDim.x + threadIdx.x;
    if (e < E) {
        const int d = ei[E + e];
        const int p = atomicAdd(&cursor[d], 1);
        srcp[p] = ei[e];
        eidp[p] = e;
        dstp[p] = d;
    }
}

// ---------------------------------------------------------------------------
// Prep: We [64][128] f32  ->  WeT [128][64] bf16 (K-major per column).
// ---------------------------------------------------------------------------
__global__ __launch_bounds__(64) void prep_we(
    const float* __restrict__ We, unsigned short* __restrict__ WeT)
{
    const int c = blockIdx.x;    // 0..127
    const int k = threadIdx.x;   // 0..63
    WeT[c * EDIM + k] = f2bf(We[k * NDIM + c]);
}

// ---------------------------------------------------------------------------
// Edge pass, MFMA + software-pipelined segmented accumulate.
// Each wave owns SPAN dst-sorted slots (4 tiles of 16). Per tile:
//   load phase (uniform sr/ds scalars + 32 x-row loads + ea A-frags, all
//   issued one tile ahead) -> MFMA -> LDS stage -> register-only flush.
// No __syncthreads; per-wave LDS region; atomics only at segment edges.
// ---------------------------------------------------------------------------
__global__ __launch_bounds__(256) void edge_mfma(
    const float* __restrict__ xnode,          // [N,128]
    const float* __restrict__ ea,             // [E,64] edge order
    const int*   __restrict__ srcp,           // [E] slot-ordered src
    const int*   __restrict__ eidp,           // [E] slot-ordered edge id
    const int*   __restrict__ dstp,           // [E] slot-ordered dst (sorted)
    const unsigned short* __restrict__ WeT,   // [128][64] bf16
    const float* __restrict__ be,             // [128]
    float*       __restrict__ aggr,           // [N,128] pre-zeroed
    int E)
{
    __shared__ float msg[WPB][16][LPAD];

    const int tid   = threadIdx.x;
    const int lane  = tid & 63;
    const int wv    = tid >> 6;
    const int span0 = (blockIdx.x * WPB + wv) * SPAN;
    if (span0 >= E) return;

    const int m16 = lane & 15;   // A row (slot-within-tile) / C col-within-ntile
    const int kg  = lane >> 4;   // k-group 0..3
    const int k0a = kg * 8;      // A/B k offset within 32-k tile

    // B fragments: full We resident (2 k-tiles x 8 n-tiles = 64 VGPR)
    short8v bfrag[2][8];
#pragma unroll
    for (int kk = 0; kk < 2; ++kk)
#pragma unroll
        for (int nt = 0; nt < 8; ++nt) {
            const int col = nt * 16 + m16;
            bfrag[kk][nt] = *reinterpret_cast<const short8v*>(&WeT[col * EDIM + kk * 32 + k0a]);
        }

    const int c0 = lane, c1 = lane + 64;
    const float be0 = be[c0], be1 = be[c1];
    float* msgw = &msg[wv][0][0];

    float a0 = 0.f, a1 = 0.f;

    if (span0 + SPAN <= E) {
        // ================= fast path (full span) =================
        int   sr_c[16], ds_c[16];
        float xv0_c[16], xv1_c[16];
        short8v af_c[2];

        // ---- prologue: tile 0 ----
#pragma unroll
        for (int s = 0; s < 16; ++s) { sr_c[s] = srcp[span0 + s]; ds_c[s] = dstp[span0 + s]; }
#pragma unroll
        for (int s = 0; s < 16; ++s) {
            xv0_c[s] = xnode[(long)sr_c[s] * NDIM + c0];
            xv1_c[s] = xnode[(long)sr_c[s] * NDIM + c1];
        }
        {
            const float* arow = ea + (long)eidp[span0 + m16] * EDIM;
            af_c[0] = cvt_row(arow, k0a);
            af_c[1] = cvt_row(arow, 32 + k0a);
        }
#pragma unroll
        for (int nt = 0; nt < 8; ++nt) {
            float4v acc = (float4v){0.f, 0.f, 0.f, 0.f};
            acc = __builtin_amdgcn_mfma_f32_16x16x32_bf16(af_c[0], bfrag[0][nt], acc, 0, 0, 0);
            acc = __builtin_amdgcn_mfma_f32_16x16x32_bf16(af_c[1], bfrag[1][nt], acc, 0, 0, 0);
#pragma unroll
            for (int r = 0; r < 4; ++r)
                msgw[(kg * 4 + r) * LPAD + nt * 16 + m16] = acc[r];
        }

        int dcur = ds_c[0];

#pragma unroll
        for (int t = 0; t < SPAN / 16; ++t) {
            const int base = span0 + t * 16;
            int   sr_n[16], ds_n[16];
            float xv0_n[16], xv1_n[16];
            short8v af_n[2];

            // ---- load phase for tile t+1 (issued before flush of t) ----
            if (t + 1 < SPAN / 16) {
#pragma unroll
                for (int s = 0; s < 16; ++s) {
                    sr_n[s] = srcp[base + 16 + s];
                    ds_n[s] = dstp[base + 16 + s];
                }
#pragma unroll
                for (int s = 0; s < 16; ++s) {
                    xv0_n[s] = xnode[(long)sr_n[s] * NDIM + c0];
                    xv1_n[s] = xnode[(long)sr_n[s] * NDIM + c1];
                }
                const float* arow = ea + (long)eidp[base + 16 + m16] * EDIM;
                af_n[0] = cvt_row(arow, k0a);
                af_n[1] = cvt_row(arow, 32 + k0a);
            }

            // ---- flush tile t: registers + LDS msg reads, no loads ----
#pragma unroll
            for (int s = 0; s < 16; ++s) {
                if (ds_c[s] != dcur) {
                    atomicAdd(&aggr[(long)dcur * NDIM + c0], a0);
                    atomicAdd(&aggr[(long)dcur * NDIM + c1], a1);
                    a0 = 0.f; a1 = 0.f; dcur = ds_c[s];
                }
                a0 += fmaxf(xv0_c[s] + msgw[s * LPAD + c0] + be0, 0.f);
                a1 += fmaxf(xv1_c[s] + msgw[s * LPAD + c1] + be1, 0.f);
            }

            // ---- MFMA + stage tile t+1 (WAR on msg: compiler lgkmcnt) ----
            if (t + 1 < SPAN / 16) {
#pragma unroll
                for (int nt = 0; nt < 8; ++nt) {
                    float4v acc = (float4v){0.f, 0.f, 0.f, 0.f};
                    acc = __builtin_amdgcn_mfma_f32_16x16x32_bf16(af_n[0], bfrag[0][nt], acc, 0, 0, 0);
                    acc = __builtin_amdgcn_mfma_f32_16x16x32_bf16(af_n[1], bfrag[1][nt], acc, 0, 0, 0);
#pragma unroll
                    for (int r = 0; r < 4; ++r)
                        msgw[(kg * 4 + r) * LPAD + nt * 16 + m16] = acc[r];
                }
                // rotate (SROA removes the copies after full unroll)
#pragma unroll
                for (int s = 0; s < 16; ++s) {
                    sr_c[s] = sr_n[s]; ds_c[s] = ds_n[s];
                    xv0_c[s] = xv0_n[s]; xv1_c[s] = xv1_n[s];
                }
            }
        }
        atomicAdd(&aggr[(long)dcur * NDIM + c0], a0);
        atomicAdd(&aggr[(long)dcur * NDIM + c1], a1);
    } else {
        // ================= tail slow path (round-5 structure) =================
        const int spanEnd = E;
        int dcur = dstp[span0];
        for (int t = 0; t < SPAN / 16; ++t) {
            const int base = span0 + t * 16;
            if (base >= spanEnd) break;

            const int  slot = (base + m16 < E) ? base + m16 : E - 1;
            const float* arow = ea + (long)eidp[slot] * EDIM;
            short8v afrag[2];
            afrag[0] = cvt_row(arow, k0a);
            afrag[1] = cvt_row(arow, 32 + k0a);

#pragma unroll
            for (int nt = 0; nt < 8; ++nt) {
                float4v acc = (float4v){0.f, 0.f, 0.f, 0.f};
                acc = __builtin_amdgcn_mfma_f32_16x16x32_bf16(afrag[0], bfrag[0][nt], acc, 0, 0, 0);
                acc = __builtin_amdgcn_mfma_f32_16x16x32_bf16(afrag[1], bfrag[1][nt], acc, 0, 0, 0);
#pragma unroll
                for (int r = 0; r < 4; ++r)
                    msgw[(kg * 4 + r) * LPAD + nt * 16 + m16] = acc[r];
            }

            for (int s = 0; s < 16; ++s) {
                const int gs = base + s;
                if (gs >= spanEnd) break;
                const int d  = dstp[gs];
                const int sr = srcp[gs];
                if (d != dcur) {
                    atomicAdd(&aggr[(long)dcur * NDIM + c0], a0);
                    atomicAdd(&aggr[(long)dcur * NDIM + c1], a1);
                    a0 = 0.f; a1 = 0.f; dcur = d;
                }
                const float xv0 = xnode[(long)sr * NDIM + c0];
                const float xv1 = xnode[(long)sr * NDIM + c1];
                a0 += fmaxf(xv0 + msgw[s * LPAD + c0] + be0, 0.f);
                a1 += fmaxf(xv1 + msgw[s * LPAD + c1] + be1, 0.f);
            }
        }
        atomicAdd(&aggr[(long)dcur * NDIM + c0], a0);
        atomicAdd(&aggr[(long)dcur * NDIM + c1], a1);
    }
}

// ---------------------------------------------------------------------------
// Node MLP: out = [relu]( relu((xin+aggr) @ Wa + ba) @ Wb + bb )
// ---------------------------------------------------------------------------
template <bool FINAL_RELU, bool STATS>
__global__ __launch_bounds__(256) void node_mlp(
    const float* xin,                   // may alias out
    const float* __restrict__ aggr,
    const float* __restrict__ Wa, const float* __restrict__ ba,
    const float* __restrict__ Wb, const float* __restrict__ bb,
    float* out,
    float* __restrict__ stats,
    int N)
{
    __shared__ __align__(16) float in_s[NDIM];
    __shared__ __align__(16) float t_s[NDIM];
    __shared__ __align__(16) float partial[NDIM];

    const int tid  = threadIdx.x;
    const int lane = tid & 63;
    const int w    = tid >> 6;
    const int kh   = w >> 1;
    const int jh   = w & 1;
    const int jf   = jh * 64 + lane;

    float wa[64], wb[64];
#pragma unroll
    for (int kk = 0; kk < 64; ++kk) {
        wa[kk] = Wa[(size_t)(kh * 64 + kk) * NDIM + jf];
        wb[kk] = Wb[(size_t)(kh * 64 + kk) * NDIM + jf];
    }
    const float baj = ba[jf];
    const float bbj = bb[jf];

    float ssum = 0.f, ssq = 0.f;

    for (int i = blockIdx.x; i < N; i += gridDim.x) {
        if (tid < NDIM)
            in_s[tid] = xin[(size_t)i * NDIM + tid] + aggr[(size_t)i * NDIM + tid];
        __syncthreads();

        float a0 = 0.f, a1 = 0.f, a2 = 0.f, a3 = 0.f;
#pragma unroll
        for (int k4 = 0; k4 < 16; ++k4) {
            const float4 v = *reinterpret_cast<const float4*>(&in_s[kh * 64 + 4 * k4]);
            a0 += v.x * wa[4 * k4 + 0];
            a1 += v.y * wa[4 * k4 + 1];
            a2 += v.z * wa[4 * k4 + 2];
            a3 += v.w * wa[4 * k4 + 3];
        }
        const float acc = (a0 + a1) + (a2 + a3);
        if (kh == 1) partial[jf] = acc;
        __syncthreads();
        if (kh == 0) {
            float t = acc + partial[jf] + baj;
            t_s[jf] = fmaxf(t, 0.f);
        }
        __syncthreads();

        float c0 = 0.f, c1 = 0.f, c2 = 0.f, c3 = 0.f;
#pragma unroll
        for (int k4 = 0; k4 < 16; ++k4) {
            const float4 v = *reinterpret_cast<const float4*>(&t_s[kh * 64 + 4 * k4]);
            c0 += v.x * wb[4 * k4 + 0];
            c1 += v.y * wb[4 * k4 + 1];
            c2 += v.z * wb[4 * k4 + 2];
            c3 += v.w * wb[4 * k4 + 3];
        }
        const float acc2 = (c0 + c1) + (c2 + c3);
        if (kh == 1) partial[jf] = acc2;
        __syncthreads();
        if (kh == 0) {
            float o = acc2 + partial[jf] + bbj;
            if (FINAL_RELU) o = fmaxf(o, 0.f);
            out[(size_t)i * NDIM + jf] = o;
            if (STATS) { ssum += o; ssq += o * o; }
        }
        __syncthreads();
    }

    if (STATS && kh == 0) {
        atomicAdd(&stats[jf], ssum);
        atomicAdd(&stats[NDIM + jf], ssq);
    }
}

// ---------------------------------------------------------------------------
// BatchNorm apply (in place).
// ---------------------------------------------------------------------------
__global__ __launch_bounds__(256) void bn_apply(
    float* out,
    const float* __restrict__ stats,
    const float* __restrict__ gamma,
    const float* __restrict__ beta,
    int N)
{
    __shared__ float sc_s[NDIM];
    __shared__ float sh_s[NDIM];
    const float invN = 1.f / (float)N;
    if (threadIdx.x < NDIM) {
        const int f = threadIdx.x;
        const float mean = stats[f] * invN;
        const float var  = stats[NDIM + f] * invN - mean * mean;
        const float sc   = gamma[f] * rsqrtf(var + BN_EPS);
        sc_s[f] = sc;
        sh_s[f] = beta[f] - mean * sc;
    }
    __syncthreads();

    const int total4 = N * (NDIM / 4);
    float4* o4 = reinterpret_cast<float4*>(out);
    for (int idx = blockIdx.x * blockDim.x + threadIdx.x; idx < total4;
         idx += gridDim.x * blockDim.x) {
        const int fb = (idx & 31) * 4;
        float4 p = o4[idx];
        p.x = p.x * sc_s[fb + 0] + sh_s[fb + 0];
        p.y = p.y * sc_s[fb + 1] + sh_s[fb + 1];
        p.z = p.z * sc_s[fb + 2] + sh_s[fb + 2];
        p.w = p.w * sc_s[fb + 3] + sh_s[fb + 3];
        o4[idx] = p;
    }
}

// ---------------------------------------------------------------------------
extern "C" void kernel_launch(void* const* d_in, const int* in_sizes, int n_in,
                              void* d_out, int out_size, void* d_ws, size_t ws_size,
                              hipStream_t stream)
{
    const float* x    = (const float*)d_in[0];
    const int*   ei   = (const int*)  d_in[1];
    const float* ea   = (const float*)d_in[2];
    const float* We1  = (const float*)d_in[3];
    const float* be1  = (const float*)d_in[4];
    const float* W1   = (const float*)d_in[5];
    const float* b1   = (const float*)d_in[6];
    const float* W2   = (const float*)d_in[7];
    const float* b2   = (const float*)d_in[8];
    const float* We2  = (const float*)d_in[9];
    const float* be2  = (const float*)d_in[10];
    const float* W3   = (const float*)d_in[11];
    const float* b3   = (const float*)d_in[12];
    const float* W4   = (const float*)d_in[13];
    const float* b4   = (const float*)d_in[14];
    const float* gamma = (const float*)d_in[15];
    const float* beta  = (const float*)d_in[16];

    const int N = in_sizes[0] / NDIM;
    const int E = in_sizes[1] / 2;

    // workspace layout (aggr first keeps 16B alignment for WeT)
    float*          aggr   = (float*)d_ws;                       // [N*128]
    unsigned short* WeT1   = (unsigned short*)(aggr + (size_t)N * NDIM); // [128*64]
    unsigned short* WeT2   = WeT1 + NDIM * EDIM;                 // [128*64]
    int*            rowptr = (int*)(WeT2 + NDIM * EDIM);         // [N+1]
    int*            cursor = rowptr + (N + 1);                   // [N]
    int*            srcp   = cursor + N;                         // [E]
    int*            eidp   = srcp + E;                           // [E]
    int*            dstp   = eidp + E;                           // [E]
    float*          stats  = (float*)(dstp + E);                 // [256]
    float*          h      = (float*)d_out;

    hipMemsetAsync(cursor, 0, (size_t)N * sizeof(int), stream);
    hipMemsetAsync(stats, 0, 2 * NDIM * sizeof(float), stream);

    // ---- CSR build (shared by both conv layers) + weight prep ----
    hist_k<<<(E + 255) / 256, 256, 0, stream>>>(ei, cursor, E);
    scan_build<<<1, 1024, 0, stream>>>(cursor, rowptr, N);
    scatter_k<<<(E + 255) / 256, 256, 0, stream>>>(ei, cursor, srcp, eidp, dstp, E);
    prep_we<<<NDIM, EDIM, 0, stream>>>(We1, WeT1);
    prep_we<<<NDIM, EDIM, 0, stream>>>(We2, WeT2);

    const int egrid = (E + WPB * SPAN - 1) / (WPB * SPAN);

    // ---- conv1 ----
    hipMemsetAsync(aggr, 0, (size_t)N * NDIM * sizeof(float), stream);
    edge_mfma<<<egrid, 256, 0, stream>>>(x, ea, srcp, eidp, dstp, WeT1, be1, aggr, E);
    node_mlp<true, false><<<2048, 256, 0, stream>>>(x, aggr, W1, b1, W2, b2,
                                                    h, nullptr, N);
    // ---- conv2 ----
    hipMemsetAsync(aggr, 0, (size_t)N * NDIM * sizeof(float), stream);
    edge_mfma<<<egrid, 256, 0, stream>>>(h, ea, srcp, eidp, dstp, WeT2, be2, aggr, E);
    node_mlp<false, true><<<2048, 256, 0, stream>>>(h, aggr, W3, b3, W4, b4,
                                                    h, stats, N);
    // ---- batch norm ----
    bn_apply<<<1024, 256, 0, stream>>>(h, stats, gamma, beta, N);
}

// Round 7
// 392.431 us; speedup vs baseline: 2.3346x; 1.3965x over previous
//
#include <hip/hip_runtime.h>

#define NDIM 128
#define EDIM 64
#define BN_EPS 1e-5f
#define SPAN 64          // slots per wave (edge pass)
#define WPB  4           // waves per block (edge pass)
#define LPAD (NDIM + 4)  // edge-pass LDS row pitch
#define PITCH 136        // node-mlp LDS row pitch in shorts (272B, 16B-mult)

typedef __attribute__((ext_vector_type(8))) short short8v;
typedef __attribute__((ext_vector_type(4))) float float4v;

static __device__ __forceinline__ unsigned short f2bf(float f) {
    union { float f; unsigned u; } c; c.f = f;
    const unsigned r = (c.u + 0x7fffu + ((c.u >> 16) & 1u)) >> 16;
    return (unsigned short)r;
}

static __device__ __forceinline__ short8v cvt_row(const float* __restrict__ arow, int k0) {
    const float4 f0 = *reinterpret_cast<const float4*>(arow + k0);
    const float4 f1 = *reinterpret_cast<const float4*>(arow + k0 + 4);
    short8v a;
    a[0] = (short)f2bf(f0.x); a[1] = (short)f2bf(f0.y);
    a[2] = (short)f2bf(f0.z); a[3] = (short)f2bf(f0.w);
    a[4] = (short)f2bf(f1.x); a[5] = (short)f2bf(f1.y);
    a[6] = (short)f2bf(f1.z); a[7] = (short)f2bf(f1.w);
    return a;
}

// ---------------------------------------------------------------------------
// CSR build step 1: degree histogram over dst.
// ---------------------------------------------------------------------------
__global__ __launch_bounds__(256) void hist_k(
    const int* __restrict__ ei, int* __restrict__ deg, int E)
{
    const int e = blockIdx.x * blockDim.x + threadIdx.x;
    if (e < E) atomicAdd(&deg[ei[E + e]], 1);
}

// ---------------------------------------------------------------------------
// CSR build step 2: exclusive scan of deg -> rowptr + cursor.
// ---------------------------------------------------------------------------
__global__ __launch_bounds__(1024) void scan_build(
    int* __restrict__ cursor, int* __restrict__ rowptr, int N)
{
    __shared__ int wsums[16];
    __shared__ int run_s;
    const int tid  = threadIdx.x;
    const int lane = tid & 63;
    const int w    = tid >> 6;
    if (tid == 0) run_s = 0;
    __syncthreads();
    for (int base = 0; base < N; base += 1024) {
        const int i = base + tid;
        const int v = (i < N) ? cursor[i] : 0;
        int incl = v;
#pragma unroll
        for (int off = 1; off < 64; off <<= 1) {
            int t = __shfl_up(incl, off, 64);
            if (lane >= off) incl += t;
        }
        if (lane == 63) wsums[w] = incl;
        __syncthreads();
        if (w == 0) {
            int s = (lane < 16) ? wsums[lane] : 0;
#pragma unroll
            for (int off = 1; off < 16; off <<= 1) {
                int t = __shfl_up(s, off, 64);
                if (lane >= off) s += t;
            }
            if (lane < 16) wsums[lane] = s;
        }
        __syncthreads();
        const int waveoff = (w > 0) ? wsums[w - 1] : 0;
        const int run = run_s;
        const int excl = run + waveoff + incl - v;
        if (i < N) { rowptr[i] = excl; cursor[i] = excl; }
        __syncthreads();
        if (tid == 0) run_s += wsums[15];
        __syncthreads();
    }
    if (tid == 0) rowptr[N] = run_s;
}

// ---------------------------------------------------------------------------
// CSR build step 3: scatter src / edge-id / dst into slot order.
// ---------------------------------------------------------------------------
__global__ __launch_bounds__(256) void scatter_k(
    const int* __restrict__ ei, int* __restrict__ cursor,
    int* __restrict__ srcp, int* __restrict__ eidp, int* __restrict__ dstp, int E)
{
    const int e = blockIdx.x * blockDim.x + threadIdx.x;
    if (e < E) {
        const int d = ei[E + e];
        const int p = atomicAdd(&cursor[d], 1);
        srcp[p] = ei[e];
        eidp[p] = e;
        dstp[p] = d;
    }
}

// ---------------------------------------------------------------------------
// Prep: We [64][128] f32  ->  WeT [128][64] bf16 (K-major per column).
// ---------------------------------------------------------------------------
__global__ __launch_bounds__(64) void prep_we(
    const float* __restrict__ We, unsigned short* __restrict__ WeT)
{
    const int c = blockIdx.x;    // 0..127
    const int k = threadIdx.x;   // 0..63
    WeT[c * EDIM + k] = f2bf(We[k * NDIM + c]);
}

// ---------------------------------------------------------------------------
// Prep: W [128][128] f32 -> WT [128][128] bf16 transposed (WT[n][k]=W[k][n]).
// ---------------------------------------------------------------------------
__global__ __launch_bounds__(128) void prep_w(
    const float* __restrict__ W, unsigned short* __restrict__ WT)
{
    const int n = blockIdx.x;    // 0..127
    const int k = threadIdx.x;   // 0..127
    WT[n * NDIM + k] = f2bf(W[k * NDIM + n]);
}

// ---------------------------------------------------------------------------
// Edge pass, MFMA + software-pipelined segmented accumulate (round-6, kept).
// ---------------------------------------------------------------------------
__global__ __launch_bounds__(256) void edge_mfma(
    const float* __restrict__ xnode,
    const float* __restrict__ ea,
    const int*   __restrict__ srcp,
    const int*   __restrict__ eidp,
    const int*   __restrict__ dstp,
    const unsigned short* __restrict__ WeT,
    const float* __restrict__ be,
    float*       __restrict__ aggr,
    int E)
{
    __shared__ float msg[WPB][16][LPAD];

    const int tid   = threadIdx.x;
    const int lane  = tid & 63;
    const int wv    = tid >> 6;
    const int span0 = (blockIdx.x * WPB + wv) * SPAN;
    if (span0 >= E) return;

    const int m16 = lane & 15;
    const int kg  = lane >> 4;
    const int k0a = kg * 8;

    short8v bfrag[2][8];
#pragma unroll
    for (int kk = 0; kk < 2; ++kk)
#pragma unroll
        for (int nt = 0; nt < 8; ++nt) {
            const int col = nt * 16 + m16;
            bfrag[kk][nt] = *reinterpret_cast<const short8v*>(&WeT[col * EDIM + kk * 32 + k0a]);
        }

    const int c0 = lane, c1 = lane + 64;
    const float be0 = be[c0], be1 = be[c1];
    float* msgw = &msg[wv][0][0];

    float a0 = 0.f, a1 = 0.f;

    if (span0 + SPAN <= E) {
        int   sr_c[16], ds_c[16];
        float xv0_c[16], xv1_c[16];
        short8v af_c[2];

#pragma unroll
        for (int s = 0; s < 16; ++s) { sr_c[s] = srcp[span0 + s]; ds_c[s] = dstp[span0 + s]; }
#pragma unroll
        for (int s = 0; s < 16; ++s) {
            xv0_c[s] = xnode[(long)sr_c[s] * NDIM + c0];
            xv1_c[s] = xnode[(long)sr_c[s] * NDIM + c1];
        }
        {
            const float* arow = ea + (long)eidp[span0 + m16] * EDIM;
            af_c[0] = cvt_row(arow, k0a);
            af_c[1] = cvt_row(arow, 32 + k0a);
        }
#pragma unroll
        for (int nt = 0; nt < 8; ++nt) {
            float4v acc = (float4v){0.f, 0.f, 0.f, 0.f};
            acc = __builtin_amdgcn_mfma_f32_16x16x32_bf16(af_c[0], bfrag[0][nt], acc, 0, 0, 0);
            acc = __builtin_amdgcn_mfma_f32_16x16x32_bf16(af_c[1], bfrag[1][nt], acc, 0, 0, 0);
#pragma unroll
            for (int r = 0; r < 4; ++r)
                msgw[(kg * 4 + r) * LPAD + nt * 16 + m16] = acc[r];
        }

        int dcur = ds_c[0];

#pragma unroll
        for (int t = 0; t < SPAN / 16; ++t) {
            const int base = span0 + t * 16;
            int   sr_n[16], ds_n[16];
            float xv0_n[16], xv1_n[16];
            short8v af_n[2];

            if (t + 1 < SPAN / 16) {
#pragma unroll
                for (int s = 0; s < 16; ++s) {
                    sr_n[s] = srcp[base + 16 + s];
                    ds_n[s] = dstp[base + 16 + s];
                }
#pragma unroll
                for (int s = 0; s < 16; ++s) {
                    xv0_n[s] = xnode[(long)sr_n[s] * NDIM + c0];
                    xv1_n[s] = xnode[(long)sr_n[s] * NDIM + c1];
                }
                const float* arow = ea + (long)eidp[base + 16 + m16] * EDIM;
                af_n[0] = cvt_row(arow, k0a);
                af_n[1] = cvt_row(arow, 32 + k0a);
            }

#pragma unroll
            for (int s = 0; s < 16; ++s) {
                if (ds_c[s] != dcur) {
                    atomicAdd(&aggr[(long)dcur * NDIM + c0], a0);
                    atomicAdd(&aggr[(long)dcur * NDIM + c1], a1);
                    a0 = 0.f; a1 = 0.f; dcur = ds_c[s];
                }
                a0 += fmaxf(xv0_c[s] + msgw[s * LPAD + c0] + be0, 0.f);
                a1 += fmaxf(xv1_c[s] + msgw[s * LPAD + c1] + be1, 0.f);
            }

            if (t + 1 < SPAN / 16) {
#pragma unroll
                for (int nt = 0; nt < 8; ++nt) {
                    float4v acc = (float4v){0.f, 0.f, 0.f, 0.f};
                    acc = __builtin_amdgcn_mfma_f32_16x16x32_bf16(af_n[0], bfrag[0][nt], acc, 0, 0, 0);
                    acc = __builtin_amdgcn_mfma_f32_16x16x32_bf16(af_n[1], bfrag[1][nt], acc, 0, 0, 0);
#pragma unroll
                    for (int r = 0; r < 4; ++r)
                        msgw[(kg * 4 + r) * LPAD + nt * 16 + m16] = acc[r];
                }
#pragma unroll
                for (int s = 0; s < 16; ++s) {
                    sr_c[s] = sr_n[s]; ds_c[s] = ds_n[s];
                    xv0_c[s] = xv0_n[s]; xv1_c[s] = xv1_n[s];
                }
            }
        }
        atomicAdd(&aggr[(long)dcur * NDIM + c0], a0);
        atomicAdd(&aggr[(long)dcur * NDIM + c1], a1);
    } else {
        const int spanEnd = E;
        int dcur = dstp[span0];
        for (int t = 0; t < SPAN / 16; ++t) {
            const int base = span0 + t * 16;
            if (base >= spanEnd) break;

            const int  slot = (base + m16 < E) ? base + m16 : E - 1;
            const float* arow = ea + (long)eidp[slot] * EDIM;
            short8v afrag[2];
            afrag[0] = cvt_row(arow, k0a);
            afrag[1] = cvt_row(arow, 32 + k0a);

#pragma unroll
            for (int nt = 0; nt < 8; ++nt) {
                float4v acc = (float4v){0.f, 0.f, 0.f, 0.f};
                acc = __builtin_amdgcn_mfma_f32_16x16x32_bf16(afrag[0], bfrag[0][nt], acc, 0, 0, 0);
                acc = __builtin_amdgcn_mfma_f32_16x16x32_bf16(afrag[1], bfrag[1][nt], acc, 0, 0, 0);
#pragma unroll
                for (int r = 0; r < 4; ++r)
                    msgw[(kg * 4 + r) * LPAD + nt * 16 + m16] = acc[r];
            }

            for (int s = 0; s < 16; ++s) {
                const int gs = base + s;
                if (gs >= spanEnd) break;
                const int d  = dstp[gs];
                const int sr = srcp[gs];
                if (d != dcur) {
                    atomicAdd(&aggr[(long)dcur * NDIM + c0], a0);
                    atomicAdd(&aggr[(long)dcur * NDIM + c1], a1);
                    a0 = 0.f; a1 = 0.f; dcur = d;
                }
                const float xv0 = xnode[(long)sr * NDIM + c0];
                const float xv1 = xnode[(long)sr * NDIM + c1];
                a0 += fmaxf(xv0 + msgw[s * LPAD + c0] + be0, 0.f);
                a1 += fmaxf(xv1 + msgw[s * LPAD + c1] + be1, 0.f);
            }
        }
        atomicAdd(&aggr[(long)dcur * NDIM + c0], a0);
        atomicAdd(&aggr[(long)dcur * NDIM + c1], a1);
    }
}

// ---------------------------------------------------------------------------
// Node MLP via MFMA. Block = 4 waves; wave wv owns features [wv*32, wv*32+32).
// Per 16-node tile: coop-load (xin+aggr)->bf16 in_lds; GEMM1 (8 MFMA/wave);
// bias+relu -> bf16 t_lds; GEMM2 (8 MFMA/wave); bias[+relu][+stats]; store.
// 2 barriers per tile. W slices register-resident bf16 fragments.
// ---------------------------------------------------------------------------
template <bool FINAL_RELU, bool STATS>
__global__ __launch_bounds__(256) void node_mlp_mfma(
    const float* xin,                    // may alias out (same-row read->write)
    const float* __restrict__ aggr,
    const unsigned short* __restrict__ W1T, const float* __restrict__ b1,
    const unsigned short* __restrict__ W2T, const float* __restrict__ b2,
    float* out,
    float* __restrict__ stats,
    int N)
{
    __shared__ unsigned short in_lds[16][PITCH];
    __shared__ unsigned short t_lds[16][PITCH];

    const int tid  = threadIdx.x;
    const int lane = tid & 63;
    const int wv   = tid >> 6;
    const int wn0  = wv * 32;
    const int m16  = lane & 15;
    const int rg   = lane >> 4;       // k-group for A/B frags, row-group for C

    // register-resident W fragments (bf16): [ktile][ntile]
    short8v b1f[4][2], b2f[4][2];
#pragma unroll
    for (int kt = 0; kt < 4; ++kt)
#pragma unroll
        for (int nt = 0; nt < 2; ++nt) {
            const int col = wn0 + nt * 16 + m16;
            b1f[kt][nt] = *reinterpret_cast<const short8v*>(&W1T[col * NDIM + kt * 32 + rg * 8]);
            b2f[kt][nt] = *reinterpret_cast<const short8v*>(&W2T[col * NDIM + kt * 32 + rg * 8]);
        }
    float bias1[2], bias2[2];
#pragma unroll
    for (int nt = 0; nt < 2; ++nt) {
        bias1[nt] = b1[wn0 + nt * 16 + m16];
        bias2[nt] = b2[wn0 + nt * 16 + m16];
    }

    float ss[2] = {0.f, 0.f}, sq[2] = {0.f, 0.f};

    const int ntile = (N + 15) >> 4;
    for (int tile = blockIdx.x; tile < ntile; tile += gridDim.x) {
        const int nb = tile << 4;

        // ---- coop load 16 rows x 128 f32 -> bf16 in_lds (coalesced) ----
        {
            const int row = tid >> 4;
            const int ch  = tid & 15;
            const int gr  = nb + row;
            short8v pk = (short8v){0, 0, 0, 0, 0, 0, 0, 0};
            if (gr < N) {
                const float4* xp = reinterpret_cast<const float4*>(xin  + (size_t)gr * NDIM + ch * 8);
                const float4* ap = reinterpret_cast<const float4*>(aggr + (size_t)gr * NDIM + ch * 8);
                const float4 x0 = xp[0], x1 = xp[1];
                const float4 g0 = ap[0], g1 = ap[1];
                pk[0] = (short)f2bf(x0.x + g0.x); pk[1] = (short)f2bf(x0.y + g0.y);
                pk[2] = (short)f2bf(x0.z + g0.z); pk[3] = (short)f2bf(x0.w + g0.w);
                pk[4] = (short)f2bf(x1.x + g1.x); pk[5] = (short)f2bf(x1.y + g1.y);
                pk[6] = (short)f2bf(x1.z + g1.z); pk[7] = (short)f2bf(x1.w + g1.w);
            }
            *reinterpret_cast<short8v*>(&in_lds[row][ch * 8]) = pk;
        }
        __syncthreads();

        // ---- GEMM1 ----
        short8v af[4];
#pragma unroll
        for (int kt = 0; kt < 4; ++kt)
            af[kt] = *reinterpret_cast<const short8v*>(&in_lds[m16][kt * 32 + rg * 8]);
        float4v acc[2];
#pragma unroll
        for (int nt = 0; nt < 2; ++nt) {
            acc[nt] = (float4v){0.f, 0.f, 0.f, 0.f};
#pragma unroll
            for (int kt = 0; kt < 4; ++kt)
                acc[nt] = __builtin_amdgcn_mfma_f32_16x16x32_bf16(af[kt], b1f[kt][nt], acc[nt], 0, 0, 0);
        }
        // bias + relu -> t_lds (bf16). D layout: col=lane&15, row=rg*4+r.
#pragma unroll
        for (int nt = 0; nt < 2; ++nt)
#pragma unroll
            for (int r = 0; r < 4; ++r) {
                const float v = fmaxf(acc[nt][r] + bias1[nt], 0.f);
                t_lds[rg * 4 + r][wn0 + nt * 16 + m16] = f2bf(v);
            }
        __syncthreads();

        // ---- GEMM2 ----
#pragma unroll
        for (int kt = 0; kt < 4; ++kt)
            af[kt] = *reinterpret_cast<const short8v*>(&t_lds[m16][kt * 32 + rg * 8]);
        float4v acc2[2];
#pragma unroll
        for (int nt = 0; nt < 2; ++nt) {
            acc2[nt] = (float4v){0.f, 0.f, 0.f, 0.f};
#pragma unroll
            for (int kt = 0; kt < 4; ++kt)
                acc2[nt] = __builtin_amdgcn_mfma_f32_16x16x32_bf16(af[kt], b2f[kt][nt], acc2[nt], 0, 0, 0);
        }

        // ---- epilogue ----
#pragma unroll
        for (int nt = 0; nt < 2; ++nt)
#pragma unroll
            for (int r = 0; r < 4; ++r) {
                const int node = nb + rg * 4 + r;
                if (node < N) {
                    float o = acc2[nt][r] + bias2[nt];
                    if (FINAL_RELU) o = fmaxf(o, 0.f);
                    out[(size_t)node * NDIM + wn0 + nt * 16 + m16] = o;
                    if (STATS) { ss[nt] += o; sq[nt] += o * o; }
                }
            }
        // 2 barriers/tile suffice: B2 orders GEMM1-reads vs next in_lds write;
        // B1(next) orders GEMM2-reads vs next t_lds write.
    }

    if (STATS) {
#pragma unroll
        for (int nt = 0; nt < 2; ++nt) {
            float s = ss[nt], q = sq[nt];
            s += __shfl_xor(s, 16); q += __shfl_xor(q, 16);
            s += __shfl_xor(s, 32); q += __shfl_xor(q, 32);
            if (rg == 0) {
                atomicAdd(&stats[wn0 + nt * 16 + m16], s);
                atomicAdd(&stats[NDIM + wn0 + nt * 16 + m16], q);
            }
        }
    }
}

// ---------------------------------------------------------------------------
// BatchNorm apply (in place).
// ---------------------------------------------------------------------------
__global__ __launch_bounds__(256) void bn_apply(
    float* out,
    const float* __restrict__ stats,
    const float* __restrict__ gamma,
    const float* __restrict__ beta,
    int N)
{
    __shared__ float sc_s[NDIM];
    __shared__ float sh_s[NDIM];
    const float invN = 1.f / (float)N;
    if (threadIdx.x < NDIM) {
        const int f = threadIdx.x;
        const float mean = stats[f] * invN;
        const float var  = stats[NDIM + f] * invN - mean * mean;
        const float sc   = gamma[f] * rsqrtf(var + BN_EPS);
        sc_s[f] = sc;
        sh_s[f] = beta[f] - mean * sc;
    }
    __syncthreads();

    const int total4 = N * (NDIM / 4);
    float4* o4 = reinterpret_cast<float4*>(out);
    for (int idx = blockIdx.x * blockDim.x + threadIdx.x; idx < total4;
         idx += gridDim.x * blockDim.x) {
        const int fb = (idx & 31) * 4;
        float4 p = o4[idx];
        p.x = p.x * sc_s[fb + 0] + sh_s[fb + 0];
        p.y = p.y * sc_s[fb + 1] + sh_s[fb + 1];
        p.z = p.z * sc_s[fb + 2] + sh_s[fb + 2];
        p.w = p.w * sc_s[fb + 3] + sh_s[fb + 3];
        o4[idx] = p;
    }
}

// ---------------------------------------------------------------------------
extern "C" void kernel_launch(void* const* d_in, const int* in_sizes, int n_in,
                              void* d_out, int out_size, void* d_ws, size_t ws_size,
                              hipStream_t stream)
{
    const float* x    = (const float*)d_in[0];
    const int*   ei   = (const int*)  d_in[1];
    const float* ea   = (const float*)d_in[2];
    const float* We1  = (const float*)d_in[3];
    const float* be1  = (const float*)d_in[4];
    const float* W1   = (const float*)d_in[5];
    const float* b1   = (const float*)d_in[6];
    const float* W2   = (const float*)d_in[7];
    const float* b2   = (const float*)d_in[8];
    const float* We2  = (const float*)d_in[9];
    const float* be2  = (const float*)d_in[10];
    const float* W3   = (const float*)d_in[11];
    const float* b3   = (const float*)d_in[12];
    const float* W4   = (const float*)d_in[13];
    const float* b4   = (const float*)d_in[14];
    const float* gamma = (const float*)d_in[15];
    const float* beta  = (const float*)d_in[16];

    const int N = in_sizes[0] / NDIM;
    const int E = in_sizes[1] / 2;

    // workspace layout (aggr first; all 16B-aligned)
    float*          aggr   = (float*)d_ws;                            // [N*128]
    unsigned short* WeT1   = (unsigned short*)(aggr + (size_t)N * NDIM);
    unsigned short* WeT2   = WeT1 + NDIM * EDIM;
    unsigned short* W1T    = WeT2 + NDIM * EDIM;                      // [128*128]
    unsigned short* W2T    = W1T + NDIM * NDIM;
    unsigned short* W3T    = W2T + NDIM * NDIM;
    unsigned short* W4T    = W3T + NDIM * NDIM;
    int*            rowptr = (int*)(W4T + NDIM * NDIM);               // [N+1]
    int*            cursor = rowptr + (N + 1);                        // [N]
    int*            srcp   = cursor + N;                              // [E]
    int*            eidp   = srcp + E;                                // [E]
    int*            dstp   = eidp + E;                                // [E]
    float*          stats  = (float*)(dstp + E);                      // [256]
    float*          h      = (float*)d_out;

    hipMemsetAsync(cursor, 0, (size_t)N * sizeof(int), stream);
    hipMemsetAsync(stats, 0, 2 * NDIM * sizeof(float), stream);

    // ---- CSR build + weight prep ----
    hist_k<<<(E + 255) / 256, 256, 0, stream>>>(ei, cursor, E);
    scan_build<<<1, 1024, 0, stream>>>(cursor, rowptr, N);
    scatter_k<<<(E + 255) / 256, 256, 0, stream>>>(ei, cursor, srcp, eidp, dstp, E);
    prep_we<<<NDIM, EDIM, 0, stream>>>(We1, WeT1);
    prep_we<<<NDIM, EDIM, 0, stream>>>(We2, WeT2);
    prep_w<<<NDIM, NDIM, 0, stream>>>(W1, W1T);
    prep_w<<<NDIM, NDIM, 0, stream>>>(W2, W2T);
    prep_w<<<NDIM, NDIM, 0, stream>>>(W3, W3T);
    prep_w<<<NDIM, NDIM, 0, stream>>>(W4, W4T);

    const int egrid = (E + WPB * SPAN - 1) / (WPB * SPAN);
    const int mgrid = 625;

    // ---- conv1 ----
    hipMemsetAsync(aggr, 0, (size_t)N * NDIM * sizeof(float), stream);
    edge_mfma<<<egrid, 256, 0, stream>>>(x, ea, srcp, eidp, dstp, WeT1, be1, aggr, E);
    node_mlp_mfma<true, false><<<mgrid, 256, 0, stream>>>(x, aggr, W1T, b1, W2T, b2,
                                                          h, nullptr, N);
    // ---- conv2 ----
    hipMemsetAsync(aggr, 0, (size_t)N * NDIM * sizeof(float), stream);
    edge_mfma<<<egrid, 256, 0, stream>>>(h, ea, srcp, eidp, dstp, WeT2, be2, aggr, E);
    node_mlp_mfma<false, true><<<mgrid, 256, 0, stream>>>(h, aggr, W3T, b3, W4T, b4,
                                                          h, stats, N);
    // ---- batch norm ----
    bn_apply<<<1024, 256, 0, stream>>>(h, stats, gamma, beta, N);
}